// Round 9
// baseline (338.344 us; speedup 1.0000x reference)
//
#include <hip/hip_runtime.h>
#include <hip/hip_bf16.h>
#include <hip/hip_fp16.h>

#define NNODES 100000
#define NEDGES 2500000
#define CIN 32
#define CHID 16
#define COUT 64
#define NGRAPH 64

#define NPB 256                 // nodes per bucket
#define NBUCKET 391             // ceil(100000/256)
#define BCAP 7424               // per-bucket capacity: mean 6394, sigma ~80 -> ~13 sigma
#define TILE 8192               // edges per binsort block
#define NTB 306                 // ceil(2.5M/8192)
#define AGG_BLK 3125            // 100000 / 32 nodes per block

typedef float vfloat4 __attribute__((ext_vector_type(4)));  // NT-load-compatible

// ---------------- workspace layout (4-byte units) ----------------------------
// gcnt  [0, 512)               int, zeroed (391 used)
// boff  [512, 1024)            int
// ginv  [1024, 1088)           f32
// offs  [1088, 101120)         int (100001 used)
// csr   [101152, 2601152)      int (src ids, dst-sorted)
// ebuf  [2601152, 5503936)     int packed (src<<8)|dst_local
// xlh   [5503936, 6303936)     f16 N*16 (3.2MB -> per-XCD L2-resident)
// xr    [6303936, 7903936)     f32 N*16
// hh    [7903936, 8703936)     f16 N*16   => 34.8 MB total
#define OFF_GCNT  0
#define OFF_BOFF  512
#define OFF_GINV  1024
#define OFF_OFFS  1088
#define OFF_CSR   101152
#define OFF_EBUF  2601152
#define OFF_XLH   5503936
#define OFF_XR    6303936
#define OFF_HH    7903936

// LDS counting-sort binning (R5/R6-proven): dense sequential bucket-run writes.
// Streaming src/dst/ebuf marked non-temporal to keep L2 clean.
__global__ __launch_bounds__(512) void binsort(const int* __restrict__ src,
                                               const int* __restrict__ dst,
                                               int* __restrict__ gcnt,
                                               int* __restrict__ ebuf) {
    __shared__ int hist[NBUCKET];
    __shared__ int binstart[NBUCKET];
    __shared__ int cursor[NBUCKET];
    __shared__ int gbase[NBUCKET];
    __shared__ int tmp[512];
    __shared__ int sbuf[TILE];
    int tid = threadIdx.x;
    int base = blockIdx.x * TILE;
    int cnt = min(NEDGES - base, TILE);
    for (int i = tid; i < NBUCKET; i += 512) hist[i] = 0;
    __syncthreads();
    int v[16], k[16];
#pragma unroll
    for (int j = 0; j < 16; j++) {
        int i = tid + j * 512;
        if (i < cnt) {
            int d = __builtin_nontemporal_load(dst + base + i);
            int s = __builtin_nontemporal_load(src + base + i);
            k[j] = d >> 8;
            v[j] = (s << 8) | (d & 255);
            atomicAdd(&hist[k[j]], 1);
        }
    }
    __syncthreads();
    int hv = (tid < NBUCKET) ? hist[tid] : 0;
    tmp[tid] = hv;
    __syncthreads();
#pragma unroll
    for (int dd = 1; dd < 512; dd <<= 1) {
        int u = (tid >= dd) ? tmp[tid - dd] : 0;
        __syncthreads();
        tmp[tid] += u;
        __syncthreads();
    }
    if (tid < NBUCKET) {
        int excl = tmp[tid] - hv;
        binstart[tid] = excl;
        cursor[tid] = excl;
        gbase[tid] = (hv > 0) ? atomicAdd(&gcnt[tid], hv) : 0;
    }
    __syncthreads();
#pragma unroll
    for (int j = 0; j < 16; j++) {
        int i = tid + j * 512;
        if (i < cnt) {
            int p = atomicAdd(&cursor[k[j]], 1);
            sbuf[p] = v[j];
        }
    }
    __syncthreads();
    int wave = tid >> 6, lane = tid & 63;
    for (int b = wave; b < NBUCKET; b += 8) {
        int c2 = hist[b];
        if (c2 == 0) continue;
        int g = gbase[b];
        int gs = min(g, BCAP);
        int ncopy = min(g + c2, BCAP) - gs;    // overflow-guarded
        int ls = binstart[b];
        int* dp = ebuf + (size_t)b * BCAP + gs;
        for (int i = lane; i < ncopy; i += 64)
            __builtin_nontemporal_store(sbuf[ls + i], dp + i);
    }
}

__device__ inline int lower_bound_i(const int* __restrict__ b, int n, int key) {
    int lo = 0, hi = n;
    while (lo < hi) {
        int m = (lo + hi) >> 1;
        if (b[m] < key) lo = m + 1; else hi = m;
    }
    return lo;
}

// block 0: exclusive scan of bucket counts; block 1: per-graph 1/count
__global__ __launch_bounds__(512) void scan_and_ginv(const int* __restrict__ gcnt,
                                                     int* __restrict__ boff,
                                                     const int* __restrict__ batch,
                                                     float* __restrict__ ginv) {
    int t = threadIdx.x;
    if (blockIdx.x == 1) {
        if (t < NGRAPH) {
            int s = lower_bound_i(batch, NNODES, t);
            int e = lower_bound_i(batch, NNODES, t + 1);
            ginv[t] = 1.0f / (float)max(e - s, 1);
        }
        return;
    }
    __shared__ int tmp[512];
    int v = (t < NBUCKET) ? min(gcnt[t], BCAP) : 0;
    tmp[t] = v;
    __syncthreads();
#pragma unroll
    for (int d = 1; d < 512; d <<= 1) {
        int u = (t >= d) ? tmp[t - d] : 0;
        __syncthreads();
        tmp[t] += u;
        __syncthreads();
    }
    if (t < NBUCKET) boff[t] = tmp[t] - v;
}

// counting-sort each bucket run into true CSR (writes confined to ~25KB window)
__global__ __launch_bounds__(256) void bucket_build(const int* __restrict__ gcnt,
                                                    const int* __restrict__ boff,
                                                    const int* __restrict__ ebuf,
                                                    int* __restrict__ csr,
                                                    int* __restrict__ offs) {
    __shared__ int hist[NPB];
    __shared__ int tmp[NPB];
    int b = blockIdx.x, tid = threadIdx.x;
    int nodes0 = b << 8;
    int nloc = min(NPB, NNODES - nodes0);
    int cnt = min(gcnt[b], BCAP);
    int base = boff[b];
    hist[tid] = 0;
    __syncthreads();
    const int* run = ebuf + (size_t)b * BCAP;
    for (int i = tid; i < cnt; i += 256)
        atomicAdd(&hist[__builtin_nontemporal_load(run + i) & 255], 1);
    __syncthreads();
    tmp[tid] = hist[tid];
    __syncthreads();
#pragma unroll
    for (int d = 1; d < NPB; d <<= 1) {
        int u = (tid >= d) ? tmp[tid - d] : 0;
        __syncthreads();
        tmp[tid] += u;
        __syncthreads();
    }
    int excl = tmp[tid] - hist[tid];
    hist[tid] = excl;
    if (tid < nloc) offs[nodes0 + tid] = base + excl;
    if (b == NBUCKET - 1 && tid == NPB - 1) offs[NNODES] = base + tmp[NPB - 1];
    __syncthreads();
    for (int i = tid; i < cnt; i += 256) {
        int v = __builtin_nontemporal_load(run + i);
        int p = atomicAdd(&hist[v & 255], 1);
        __builtin_nontemporal_store(v >> 8, csr + base + p);
    }
}

// xl(f16) = x @ w1_l.T ; xr(f32) = x @ w1_r.T + b1
__global__ __launch_bounds__(256) void transform1(const float* __restrict__ x,
                                                  const float* __restrict__ w1l,
                                                  const float* __restrict__ b1,
                                                  const float* __restrict__ w1r,
                                                  __half2* __restrict__ xlh2,
                                                  float* __restrict__ xr) {
    __shared__ float wl[CHID * CIN];
    __shared__ float wr[CHID * CIN];
    __shared__ float bs[CHID];
    for (int i = threadIdx.x; i < CHID * CIN; i += 256) { wl[i] = w1l[i]; wr[i] = w1r[i]; }
    if (threadIdx.x < CHID) bs[threadIdx.x] = b1[threadIdx.x];
    __syncthreads();
    int n = blockIdx.x * 256 + threadIdx.x;
    if (n >= NNODES) return;
    float xv[CIN];
    const vfloat4* x4 = (const vfloat4*)(x + (size_t)n * CIN);
#pragma unroll
    for (int q = 0; q < CIN / 4; q++) {
        vfloat4 v = __builtin_nontemporal_load(x4 + q);
        xv[4*q] = v.x; xv[4*q+1] = v.y; xv[4*q+2] = v.z; xv[4*q+3] = v.w;
    }
    float oL[CHID];
#pragma unroll
    for (int o = 0; o < CHID; o++) {
        float aL = 0.f, aR = bs[o];
#pragma unroll
        for (int i = 0; i < CIN; i++) {
            aL = fmaf(wl[o * CIN + i], xv[i], aL);
            aR = fmaf(wr[o * CIN + i], xv[i], aR);
        }
        oL[o] = aL;
        __builtin_nontemporal_store(aR, xr + (size_t)n * CHID + o);
    }
#pragma unroll
    for (int q = 0; q < CHID / 2; q++)
        xlh2[(size_t)n * 8 + q] = __floats2half2_rn(oL[2*q], oL[2*q+1]);
}

// layer-1 aggregate + finalize: h(f16) = relu(mean_in(xl[src]) + xr)
// 8 lanes per node, half2 (4B) gathers: half the mem instrs of R7, 32 nodes/block-row
__global__ __launch_bounds__(256) void agg1_fused(const int* __restrict__ offs,
                                                  const int* __restrict__ csr,
                                                  const __half2* __restrict__ xlh2,
                                                  const float* __restrict__ xr,
                                                  __half2* __restrict__ hh2) {
    int node = blockIdx.x * 32 + (threadIdx.x >> 3);
    int c2 = threadIdx.x & 7;          // half2 index: channels 2c2, 2c2+1
    int s0 = offs[node], s1 = offs[node + 1];
    float2 a0 = {0,0}, a1 = {0,0}, a2 = {0,0}, a3 = {0,0};
    float2 a4 = {0,0}, a5 = {0,0}, a6 = {0,0}, a7 = {0,0};
    int p = s0;
    for (; p + 7 < s1; p += 8) {
        int sA = __builtin_nontemporal_load(csr + p);
        int sB = __builtin_nontemporal_load(csr + p + 1);
        int sC = __builtin_nontemporal_load(csr + p + 2);
        int sD = __builtin_nontemporal_load(csr + p + 3);
        int sE = __builtin_nontemporal_load(csr + p + 4);
        int sF = __builtin_nontemporal_load(csr + p + 5);
        int sG = __builtin_nontemporal_load(csr + p + 6);
        int sH = __builtin_nontemporal_load(csr + p + 7);
        float2 vA = __half22float2(xlh2[(size_t)sA * 8 + c2]);
        float2 vB = __half22float2(xlh2[(size_t)sB * 8 + c2]);
        float2 vC = __half22float2(xlh2[(size_t)sC * 8 + c2]);
        float2 vD = __half22float2(xlh2[(size_t)sD * 8 + c2]);
        float2 vE = __half22float2(xlh2[(size_t)sE * 8 + c2]);
        float2 vF = __half22float2(xlh2[(size_t)sF * 8 + c2]);
        float2 vG = __half22float2(xlh2[(size_t)sG * 8 + c2]);
        float2 vH = __half22float2(xlh2[(size_t)sH * 8 + c2]);
        a0.x += vA.x; a0.y += vA.y;  a1.x += vB.x; a1.y += vB.y;
        a2.x += vC.x; a2.y += vC.y;  a3.x += vD.x; a3.y += vD.y;
        a4.x += vE.x; a4.y += vE.y;  a5.x += vF.x; a5.y += vF.y;
        a6.x += vG.x; a6.y += vG.y;  a7.x += vH.x; a7.y += vH.y;
    }
    for (; p < s1; p++) {
        float2 v = __half22float2(xlh2[(size_t)__builtin_nontemporal_load(csr + p) * 8 + c2]);
        a0.x += v.x; a0.y += v.y;
    }
    float sx = ((a0.x + a1.x) + (a2.x + a3.x)) + ((a4.x + a5.x) + (a6.x + a7.x));
    float sy = ((a0.y + a1.y) + (a2.y + a3.y)) + ((a4.y + a5.y) + (a6.y + a7.y));
    float inv = 1.0f / (float)max(s1 - s0, 1);
    const float2* xr2 = (const float2*)xr;
    float2 r = xr2[(size_t)node * 8 + c2];
    float hx = fmaxf(fmaf(sx, inv, r.x), 0.f);
    float hy = fmaxf(fmaf(sy, inv, r.y), 0.f);
    hh2[(size_t)node * 8 + c2] = __floats2half2_rn(hx, hy);
}

// layer-2 aggregate + output transform + fused graph pooling (8 lanes/node)
__global__ __launch_bounds__(256) void agg2_pool(const int* __restrict__ offs,
                                                 const int* __restrict__ csr,
                                                 const __half2* __restrict__ hh2,
                                                 const float* __restrict__ w2l,
                                                 const float* __restrict__ b2,
                                                 const float* __restrict__ w2r,
                                                 const int* __restrict__ batch,
                                                 const float* __restrict__ ginv,
                                                 float* __restrict__ out) {
    __shared__ float wlT[CHID * COUT];      // transposed: broadcast-friendly
    __shared__ float wrT[CHID * COUT];
    __shared__ float bs[COUT];
    __shared__ float mean_s[32 * CHID];
    __shared__ float pool[4 * COUT];        // 32-node window spans <=2 graphs (~1563/graph)
    __shared__ int used[4];
    for (int idx = threadIdx.x; idx < CHID * COUT; idx += 256) {
        int i = idx >> 6, o = idx & 63;
        wlT[idx] = w2l[o * CHID + i];
        wrT[idx] = w2r[o * CHID + i];
    }
    if (threadIdx.x < COUT) bs[threadIdx.x] = b2[threadIdx.x];
    for (int idx = threadIdx.x; idx < 4 * COUT; idx += 256) pool[idx] = 0.f;
    if (threadIdx.x < 4) used[threadIdx.x] = 0;
    __syncthreads();

    int g = threadIdx.x >> 3;               // 0..31 node groups
    int c2 = threadIdx.x & 7;
    int node = blockIdx.x * 32 + g;         // grid exact: 3125*32 = 100000
    int gbase = batch[blockIdx.x * 32];
    int gid = batch[node];
    int gloc = min(gid - gbase, 3);
    float gw = ginv[gid];
    if (c2 == 0) used[gloc] = 1;

    int s0 = offs[node], s1 = offs[node + 1];
    float2 a0 = {0,0}, a1 = {0,0}, a2 = {0,0}, a3 = {0,0};
    float2 a4 = {0,0}, a5 = {0,0}, a6 = {0,0}, a7 = {0,0};
    int p = s0;
    for (; p + 7 < s1; p += 8) {
        int sA = __builtin_nontemporal_load(csr + p);
        int sB = __builtin_nontemporal_load(csr + p + 1);
        int sC = __builtin_nontemporal_load(csr + p + 2);
        int sD = __builtin_nontemporal_load(csr + p + 3);
        int sE = __builtin_nontemporal_load(csr + p + 4);
        int sF = __builtin_nontemporal_load(csr + p + 5);
        int sG = __builtin_nontemporal_load(csr + p + 6);
        int sH = __builtin_nontemporal_load(csr + p + 7);
        float2 vA = __half22float2(hh2[(size_t)sA * 8 + c2]);
        float2 vB = __half22float2(hh2[(size_t)sB * 8 + c2]);
        float2 vC = __half22float2(hh2[(size_t)sC * 8 + c2]);
        float2 vD = __half22float2(hh2[(size_t)sD * 8 + c2]);
        float2 vE = __half22float2(hh2[(size_t)sE * 8 + c2]);
        float2 vF = __half22float2(hh2[(size_t)sF * 8 + c2]);
        float2 vG = __half22float2(hh2[(size_t)sG * 8 + c2]);
        float2 vH = __half22float2(hh2[(size_t)sH * 8 + c2]);
        a0.x += vA.x; a0.y += vA.y;  a1.x += vB.x; a1.y += vB.y;
        a2.x += vC.x; a2.y += vC.y;  a3.x += vD.x; a3.y += vD.y;
        a4.x += vE.x; a4.y += vE.y;  a5.x += vF.x; a5.y += vF.y;
        a6.x += vG.x; a6.y += vG.y;  a7.x += vH.x; a7.y += vH.y;
    }
    for (; p < s1; p++) {
        float2 v = __half22float2(hh2[(size_t)__builtin_nontemporal_load(csr + p) * 8 + c2]);
        a0.x += v.x; a0.y += v.y;
    }
    float sx = ((a0.x + a1.x) + (a2.x + a3.x)) + ((a4.x + a5.x) + (a6.x + a7.x));
    float sy = ((a0.y + a1.y) + (a2.y + a3.y)) + ((a4.y + a5.y) + (a6.y + a7.y));
    float inv = 1.0f / (float)max(s1 - s0, 1);
    float2* ms2 = (float2*)mean_s;
    ms2[g * 8 + c2] = make_float2(sx * inv, sy * inv);
    __syncthreads();

    float hv[CHID], m[CHID];
    const __half2* hp = hh2 + (size_t)node * 8;
#pragma unroll
    for (int q = 0; q < CHID / 2; q++) {
        float2 f = __half22float2(hp[q]);
        hv[2*q] = f.x; hv[2*q+1] = f.y;
    }
#pragma unroll
    for (int i = 0; i < CHID; i++) m[i] = mean_s[g * CHID + i];

#pragma unroll
    for (int k = 0; k < 8; k++) {
        int o = c2 + 8 * k;
        float s = bs[o];
#pragma unroll
        for (int i = 0; i < CHID; i++) {
            s = fmaf(wlT[i * COUT + o], m[i], s);
            s = fmaf(wrT[i * COUT + o], hv[i], s);
        }
        atomicAdd(&pool[gloc * COUT + o], s * gw);
    }
    __syncthreads();
    for (int idx = threadIdx.x; idx < 4 * COUT; idx += 256) {
        int row = idx >> 6;
        if (used[row]) atomicAdd(&out[(gbase + row) * COUT + (idx & 63)], pool[idx]);
    }
}

extern "C" void kernel_launch(void* const* d_in, const int* in_sizes, int n_in,
                              void* d_out, int out_size, void* d_ws, size_t ws_size,
                              hipStream_t stream) {
    const float* x    = (const float*)d_in[0];
    const int*   ei   = (const int*)d_in[1];   // [2, E] int32
    const int*   batch= (const int*)d_in[2];
    const float* w1l  = (const float*)d_in[3];
    const float* b1   = (const float*)d_in[4];
    const float* w1r  = (const float*)d_in[5];
    const float* w2l  = (const float*)d_in[6];
    const float* b2   = (const float*)d_in[7];
    const float* w2r  = (const float*)d_in[8];
    float* out = (float*)d_out;

    const int* src = ei;
    const int* dst = ei + NEDGES;

    int*     ws_i = (int*)d_ws;
    float*   ws_f = (float*)d_ws;
    int*     gcnt = ws_i + OFF_GCNT;
    int*     boff = ws_i + OFF_BOFF;
    float*   ginv = ws_f + OFF_GINV;
    int*     offs = ws_i + OFF_OFFS;
    int*     csr  = ws_i + OFF_CSR;
    int*     ebuf = ws_i + OFF_EBUF;
    __half2* xlh2 = (__half2*)(ws_i + OFF_XLH);
    float*   xr   = ws_f + OFF_XR;
    __half2* hh2  = (__half2*)(ws_i + OFF_HH);

    (void)hipMemsetAsync(gcnt, 0, 512 * sizeof(int), stream);
    (void)hipMemsetAsync(out, 0, NGRAPH * COUT * sizeof(float), stream);

    int nbl = (NNODES + 255) / 256;   // 391

    binsort      <<<NTB, 512, 0, stream>>>(src, dst, gcnt, ebuf);
    transform1   <<<nbl, 256, 0, stream>>>(x, w1l, b1, w1r, xlh2, xr);
    scan_and_ginv<<<2, 512, 0, stream>>>(gcnt, boff, batch, ginv);
    bucket_build <<<NBUCKET, 256, 0, stream>>>(gcnt, boff, ebuf, csr, offs);
    agg1_fused   <<<AGG_BLK, 256, 0, stream>>>(offs, csr, xlh2, xr, hh2);
    agg2_pool    <<<AGG_BLK, 256, 0, stream>>>(offs, csr, hh2, w2l, b2, w2r, batch, ginv, out);
}

// Round 10
// 248.147 us; speedup vs baseline: 1.3635x; 1.3635x over previous
//
#include <hip/hip_runtime.h>
#include <hip/hip_bf16.h>
#include <hip/hip_fp16.h>

#define NNODES 100000
#define NEDGES 2500000
#define CIN 32
#define CHID 16
#define COUT 64
#define NGRAPH 64

#define NPB 256                 // nodes per bucket
#define NBUCKET 391             // ceil(100000/256)
#define BCAP 7424               // per-bucket capacity: mean 6394, sigma ~80 -> ~13 sigma
#define TILE 8192               // edges per binsort block
#define NTB 306                 // ceil(2.5M/8192)
#define AGG_BLK 3125            // 100000 / 32 nodes per block

// ---------------- workspace layout (4-byte units) ----------------------------
// gcnt  [0, 512)               int, zeroed (391 used)
// boff  [512, 1024)            int
// ginv  [1024, 1088)           f32
// offs  [1088, 101120)         int (100001 used)
// csr   [101152, 2601152)      int (src ids, dst-sorted)
// ebuf  [2601152, 5503936)     int packed (src<<8)|dst_local
// xlh   [5503936, 6303936)     f16 N*16 (3.2MB -> per-XCD L2-resident)
// xr    [6303936, 7903936)     f32 N*16
// hh    [7903936, 8703936)     f16 N*16   => 34.8 MB total
#define OFF_GCNT  0
#define OFF_BOFF  512
#define OFF_GINV  1024
#define OFF_OFFS  1088
#define OFF_CSR   101152
#define OFF_EBUF  2601152
#define OFF_XLH   5503936
#define OFF_XR    6303936
#define OFF_HH    7903936

// LDS counting-sort binning (R5/R6-proven): dense sequential bucket-run writes.
// NO non-temporal hints (R9 lesson: NT on the producer->consumer chain costs
// more in lost L2 reuse than it saves).
__global__ __launch_bounds__(512) void binsort(const int* __restrict__ src,
                                               const int* __restrict__ dst,
                                               int* __restrict__ gcnt,
                                               int* __restrict__ ebuf) {
    __shared__ int hist[NBUCKET];
    __shared__ int binstart[NBUCKET];
    __shared__ int cursor[NBUCKET];
    __shared__ int gbase[NBUCKET];
    __shared__ int tmp[512];
    __shared__ int sbuf[TILE];
    int tid = threadIdx.x;
    int base = blockIdx.x * TILE;
    int cnt = min(NEDGES - base, TILE);
    for (int i = tid; i < NBUCKET; i += 512) hist[i] = 0;
    __syncthreads();
    int v[16], k[16];
#pragma unroll
    for (int j = 0; j < 16; j++) {
        int i = tid + j * 512;
        if (i < cnt) {
            int d = dst[base + i], s = src[base + i];
            k[j] = d >> 8;
            v[j] = (s << 8) | (d & 255);
            atomicAdd(&hist[k[j]], 1);
        }
    }
    __syncthreads();
    int hv = (tid < NBUCKET) ? hist[tid] : 0;
    tmp[tid] = hv;
    __syncthreads();
#pragma unroll
    for (int dd = 1; dd < 512; dd <<= 1) {
        int u = (tid >= dd) ? tmp[tid - dd] : 0;
        __syncthreads();
        tmp[tid] += u;
        __syncthreads();
    }
    if (tid < NBUCKET) {
        int excl = tmp[tid] - hv;
        binstart[tid] = excl;
        cursor[tid] = excl;
        gbase[tid] = (hv > 0) ? atomicAdd(&gcnt[tid], hv) : 0;
    }
    __syncthreads();
#pragma unroll
    for (int j = 0; j < 16; j++) {
        int i = tid + j * 512;
        if (i < cnt) {
            int p = atomicAdd(&cursor[k[j]], 1);
            sbuf[p] = v[j];
        }
    }
    __syncthreads();
    int wave = tid >> 6, lane = tid & 63;
    for (int b = wave; b < NBUCKET; b += 8) {
        int c2 = hist[b];
        if (c2 == 0) continue;
        int g = gbase[b];
        int gs = min(g, BCAP);
        int ncopy = min(g + c2, BCAP) - gs;    // overflow-guarded
        int ls = binstart[b];
        int* dp = ebuf + (size_t)b * BCAP + gs;
        for (int i = lane; i < ncopy; i += 64) dp[i] = sbuf[ls + i];
    }
}

__device__ inline int lower_bound_i(const int* __restrict__ b, int n, int key) {
    int lo = 0, hi = n;
    while (lo < hi) {
        int m = (lo + hi) >> 1;
        if (b[m] < key) lo = m + 1; else hi = m;
    }
    return lo;
}

// block 0: exclusive scan of bucket counts; block 1: per-graph 1/count
__global__ __launch_bounds__(512) void scan_and_ginv(const int* __restrict__ gcnt,
                                                     int* __restrict__ boff,
                                                     const int* __restrict__ batch,
                                                     float* __restrict__ ginv) {
    int t = threadIdx.x;
    if (blockIdx.x == 1) {
        if (t < NGRAPH) {
            int s = lower_bound_i(batch, NNODES, t);
            int e = lower_bound_i(batch, NNODES, t + 1);
            ginv[t] = 1.0f / (float)max(e - s, 1);
        }
        return;
    }
    __shared__ int tmp[512];
    int v = (t < NBUCKET) ? min(gcnt[t], BCAP) : 0;
    tmp[t] = v;
    __syncthreads();
#pragma unroll
    for (int d = 1; d < 512; d <<= 1) {
        int u = (t >= d) ? tmp[t - d] : 0;
        __syncthreads();
        tmp[t] += u;
        __syncthreads();
    }
    if (t < NBUCKET) boff[t] = tmp[t] - v;
}

// counting-sort each bucket run into true CSR. The run is staged in LDS ONCE
// (R9 read it from global twice); histogram + scatter both hit LDS.
__global__ __launch_bounds__(256) void bucket_build(const int* __restrict__ gcnt,
                                                    const int* __restrict__ boff,
                                                    const int* __restrict__ ebuf,
                                                    int* __restrict__ csr,
                                                    int* __restrict__ offs) {
    __shared__ int sbuf[BCAP];            // 29.7 KB
    __shared__ int hist[NPB];
    __shared__ int tmp[NPB];
    int b = blockIdx.x, tid = threadIdx.x;
    int nodes0 = b << 8;
    int nloc = min(NPB, NNODES - nodes0);
    int cnt = min(gcnt[b], BCAP);
    int base = boff[b];
    hist[tid] = 0;
    const int* run = ebuf + (size_t)b * BCAP;
    for (int i = tid; i < cnt; i += 256) sbuf[i] = run[i];
    __syncthreads();
    for (int i = tid; i < cnt; i += 256) atomicAdd(&hist[sbuf[i] & 255], 1);
    __syncthreads();
    tmp[tid] = hist[tid];
    __syncthreads();
#pragma unroll
    for (int d = 1; d < NPB; d <<= 1) {
        int u = (tid >= d) ? tmp[tid - d] : 0;
        __syncthreads();
        tmp[tid] += u;
        __syncthreads();
    }
    int excl = tmp[tid] - hist[tid];
    hist[tid] = excl;
    if (tid < nloc) offs[nodes0 + tid] = base + excl;
    if (b == NBUCKET - 1 && tid == NPB - 1) offs[NNODES] = base + tmp[NPB - 1];
    __syncthreads();
    for (int i = tid; i < cnt; i += 256) {
        int v = sbuf[i];
        int p = atomicAdd(&hist[v & 255], 1);
        csr[base + p] = v >> 8;
    }
}

// xl(f16) = x @ w1_l.T ; xr(f32) = x @ w1_r.T + b1
__global__ __launch_bounds__(256) void transform1(const float* __restrict__ x,
                                                  const float* __restrict__ w1l,
                                                  const float* __restrict__ b1,
                                                  const float* __restrict__ w1r,
                                                  __half2* __restrict__ xlh2,
                                                  float* __restrict__ xr) {
    __shared__ float wl[CHID * CIN];
    __shared__ float wr[CHID * CIN];
    __shared__ float bs[CHID];
    for (int i = threadIdx.x; i < CHID * CIN; i += 256) { wl[i] = w1l[i]; wr[i] = w1r[i]; }
    if (threadIdx.x < CHID) bs[threadIdx.x] = b1[threadIdx.x];
    __syncthreads();
    int n = blockIdx.x * 256 + threadIdx.x;
    if (n >= NNODES) return;
    float xv[CIN];
    const float4* x4 = (const float4*)(x + (size_t)n * CIN);
#pragma unroll
    for (int q = 0; q < CIN / 4; q++) {
        float4 v = x4[q];
        xv[4*q] = v.x; xv[4*q+1] = v.y; xv[4*q+2] = v.z; xv[4*q+3] = v.w;
    }
    float oL[CHID];
#pragma unroll
    for (int o = 0; o < CHID; o++) {
        float aL = 0.f, aR = bs[o];
#pragma unroll
        for (int i = 0; i < CIN; i++) {
            aL = fmaf(wl[o * CIN + i], xv[i], aL);
            aR = fmaf(wr[o * CIN + i], xv[i], aR);
        }
        oL[o] = aL;
        xr[(size_t)n * CHID + o] = aR;
    }
#pragma unroll
    for (int q = 0; q < CHID / 2; q++)
        xlh2[(size_t)n * 8 + q] = __floats2half2_rn(oL[2*q], oL[2*q+1]);
}

// layer-1 aggregate + finalize: h(f16) = relu(mean_in(xl[src]) + xr)
// 8 lanes per node, half2 (4B) gathers (R9-proven structure, NT removed)
__global__ __launch_bounds__(256) void agg1_fused(const int* __restrict__ offs,
                                                  const int* __restrict__ csr,
                                                  const __half2* __restrict__ xlh2,
                                                  const float* __restrict__ xr,
                                                  __half2* __restrict__ hh2) {
    int node = blockIdx.x * 32 + (threadIdx.x >> 3);
    int c2 = threadIdx.x & 7;          // half2 index: channels 2c2, 2c2+1
    int s0 = offs[node], s1 = offs[node + 1];
    float2 a0 = {0,0}, a1 = {0,0}, a2 = {0,0}, a3 = {0,0};
    float2 a4 = {0,0}, a5 = {0,0}, a6 = {0,0}, a7 = {0,0};
    int p = s0;
    for (; p + 7 < s1; p += 8) {
        int sA = csr[p],     sB = csr[p + 1], sC = csr[p + 2], sD = csr[p + 3];
        int sE = csr[p + 4], sF = csr[p + 5], sG = csr[p + 6], sH = csr[p + 7];
        float2 vA = __half22float2(xlh2[(size_t)sA * 8 + c2]);
        float2 vB = __half22float2(xlh2[(size_t)sB * 8 + c2]);
        float2 vC = __half22float2(xlh2[(size_t)sC * 8 + c2]);
        float2 vD = __half22float2(xlh2[(size_t)sD * 8 + c2]);
        float2 vE = __half22float2(xlh2[(size_t)sE * 8 + c2]);
        float2 vF = __half22float2(xlh2[(size_t)sF * 8 + c2]);
        float2 vG = __half22float2(xlh2[(size_t)sG * 8 + c2]);
        float2 vH = __half22float2(xlh2[(size_t)sH * 8 + c2]);
        a0.x += vA.x; a0.y += vA.y;  a1.x += vB.x; a1.y += vB.y;
        a2.x += vC.x; a2.y += vC.y;  a3.x += vD.x; a3.y += vD.y;
        a4.x += vE.x; a4.y += vE.y;  a5.x += vF.x; a5.y += vF.y;
        a6.x += vG.x; a6.y += vG.y;  a7.x += vH.x; a7.y += vH.y;
    }
    for (; p < s1; p++) {
        float2 v = __half22float2(xlh2[(size_t)csr[p] * 8 + c2]);
        a0.x += v.x; a0.y += v.y;
    }
    float sx = ((a0.x + a1.x) + (a2.x + a3.x)) + ((a4.x + a5.x) + (a6.x + a7.x));
    float sy = ((a0.y + a1.y) + (a2.y + a3.y)) + ((a4.y + a5.y) + (a6.y + a7.y));
    float inv = 1.0f / (float)max(s1 - s0, 1);
    const float2* xr2 = (const float2*)xr;
    float2 r = xr2[(size_t)node * 8 + c2];
    float hx = fmaxf(fmaf(sx, inv, r.x), 0.f);
    float hy = fmaxf(fmaf(sy, inv, r.y), 0.f);
    hh2[(size_t)node * 8 + c2] = __floats2half2_rn(hx, hy);
}

// layer-2 aggregate + output transform + fused graph pooling (8 lanes/node)
__global__ __launch_bounds__(256) void agg2_pool(const int* __restrict__ offs,
                                                 const int* __restrict__ csr,
                                                 const __half2* __restrict__ hh2,
                                                 const float* __restrict__ w2l,
                                                 const float* __restrict__ b2,
                                                 const float* __restrict__ w2r,
                                                 const int* __restrict__ batch,
                                                 const float* __restrict__ ginv,
                                                 float* __restrict__ out) {
    __shared__ float wlT[CHID * COUT];      // transposed: broadcast-friendly
    __shared__ float wrT[CHID * COUT];
    __shared__ float bs[COUT];
    __shared__ float mean_s[32 * CHID];
    __shared__ float pool[4 * COUT];        // 32-node window spans <=2 graphs (~1563/graph)
    __shared__ int used[4];
    for (int idx = threadIdx.x; idx < CHID * COUT; idx += 256) {
        int i = idx >> 6, o = idx & 63;
        wlT[idx] = w2l[o * CHID + i];
        wrT[idx] = w2r[o * CHID + i];
    }
    if (threadIdx.x < COUT) bs[threadIdx.x] = b2[threadIdx.x];
    for (int idx = threadIdx.x; idx < 4 * COUT; idx += 256) pool[idx] = 0.f;
    if (threadIdx.x < 4) used[threadIdx.x] = 0;
    __syncthreads();

    int g = threadIdx.x >> 3;               // 0..31 node groups
    int c2 = threadIdx.x & 7;
    int node = blockIdx.x * 32 + g;         // grid exact: 3125*32 = 100000
    int gbase = batch[blockIdx.x * 32];
    int gid = batch[node];
    int gloc = min(gid - gbase, 3);
    float gw = ginv[gid];
    if (c2 == 0) used[gloc] = 1;

    int s0 = offs[node], s1 = offs[node + 1];
    float2 a0 = {0,0}, a1 = {0,0}, a2 = {0,0}, a3 = {0,0};
    float2 a4 = {0,0}, a5 = {0,0}, a6 = {0,0}, a7 = {0,0};
    int p = s0;
    for (; p + 7 < s1; p += 8) {
        int sA = csr[p],     sB = csr[p + 1], sC = csr[p + 2], sD = csr[p + 3];
        int sE = csr[p + 4], sF = csr[p + 5], sG = csr[p + 6], sH = csr[p + 7];
        float2 vA = __half22float2(hh2[(size_t)sA * 8 + c2]);
        float2 vB = __half22float2(hh2[(size_t)sB * 8 + c2]);
        float2 vC = __half22float2(hh2[(size_t)sC * 8 + c2]);
        float2 vD = __half22float2(hh2[(size_t)sD * 8 + c2]);
        float2 vE = __half22float2(hh2[(size_t)sE * 8 + c2]);
        float2 vF = __half22float2(hh2[(size_t)sF * 8 + c2]);
        float2 vG = __half22float2(hh2[(size_t)sG * 8 + c2]);
        float2 vH = __half22float2(hh2[(size_t)sH * 8 + c2]);
        a0.x += vA.x; a0.y += vA.y;  a1.x += vB.x; a1.y += vB.y;
        a2.x += vC.x; a2.y += vC.y;  a3.x += vD.x; a3.y += vD.y;
        a4.x += vE.x; a4.y += vE.y;  a5.x += vF.x; a5.y += vF.y;
        a6.x += vG.x; a6.y += vG.y;  a7.x += vH.x; a7.y += vH.y;
    }
    for (; p < s1; p++) {
        float2 v = __half22float2(hh2[(size_t)csr[p] * 8 + c2]);
        a0.x += v.x; a0.y += v.y;
    }
    float sx = ((a0.x + a1.x) + (a2.x + a3.x)) + ((a4.x + a5.x) + (a6.x + a7.x));
    float sy = ((a0.y + a1.y) + (a2.y + a3.y)) + ((a4.y + a5.y) + (a6.y + a7.y));
    float inv = 1.0f / (float)max(s1 - s0, 1);
    float2* ms2 = (float2*)mean_s;
    ms2[g * 8 + c2] = make_float2(sx * inv, sy * inv);
    __syncthreads();

    float hv[CHID], m[CHID];
    const __half2* hp = hh2 + (size_t)node * 8;
#pragma unroll
    for (int q = 0; q < CHID / 2; q++) {
        float2 f = __half22float2(hp[q]);
        hv[2*q] = f.x; hv[2*q+1] = f.y;
    }
#pragma unroll
    for (int i = 0; i < CHID; i++) m[i] = mean_s[g * CHID + i];

#pragma unroll
    for (int k = 0; k < 8; k++) {
        int o = c2 + 8 * k;
        float s = bs[o];
#pragma unroll
        for (int i = 0; i < CHID; i++) {
            s = fmaf(wlT[i * COUT + o], m[i], s);
            s = fmaf(wrT[i * COUT + o], hv[i], s);
        }
        atomicAdd(&pool[gloc * COUT + o], s * gw);
    }
    __syncthreads();
    for (int idx = threadIdx.x; idx < 4 * COUT; idx += 256) {
        int row = idx >> 6;
        if (used[row]) atomicAdd(&out[(gbase + row) * COUT + (idx & 63)], pool[idx]);
    }
}

extern "C" void kernel_launch(void* const* d_in, const int* in_sizes, int n_in,
                              void* d_out, int out_size, void* d_ws, size_t ws_size,
                              hipStream_t stream) {
    const float* x    = (const float*)d_in[0];
    const int*   ei   = (const int*)d_in[1];   // [2, E] int32
    const int*   batch= (const int*)d_in[2];
    const float* w1l  = (const float*)d_in[3];
    const float* b1   = (const float*)d_in[4];
    const float* w1r  = (const float*)d_in[5];
    const float* w2l  = (const float*)d_in[6];
    const float* b2   = (const float*)d_in[7];
    const float* w2r  = (const float*)d_in[8];
    float* out = (float*)d_out;

    const int* src = ei;
    const int* dst = ei + NEDGES;

    int*     ws_i = (int*)d_ws;
    float*   ws_f = (float*)d_ws;
    int*     gcnt = ws_i + OFF_GCNT;
    int*     boff = ws_i + OFF_BOFF;
    float*   ginv = ws_f + OFF_GINV;
    int*     offs = ws_i + OFF_OFFS;
    int*     csr  = ws_i + OFF_CSR;
    int*     ebuf = ws_i + OFF_EBUF;
    __half2* xlh2 = (__half2*)(ws_i + OFF_XLH);
    float*   xr   = ws_f + OFF_XR;
    __half2* hh2  = (__half2*)(ws_i + OFF_HH);

    (void)hipMemsetAsync(gcnt, 0, 512 * sizeof(int), stream);
    (void)hipMemsetAsync(out, 0, NGRAPH * COUT * sizeof(float), stream);

    int nbl = (NNODES + 255) / 256;   // 391

    binsort      <<<NTB, 512, 0, stream>>>(src, dst, gcnt, ebuf);
    transform1   <<<nbl, 256, 0, stream>>>(x, w1l, b1, w1r, xlh2, xr);
    scan_and_ginv<<<2, 512, 0, stream>>>(gcnt, boff, batch, ginv);
    bucket_build <<<NBUCKET, 256, 0, stream>>>(gcnt, boff, ebuf, csr, offs);
    agg1_fused   <<<AGG_BLK, 256, 0, stream>>>(offs, csr, xlh2, xr, hh2);
    agg2_pool    <<<AGG_BLK, 256, 0, stream>>>(offs, csr, hh2, w2l, b2, w2r, batch, ginv, out);
}

// Round 11
// 243.511 us; speedup vs baseline: 1.3894x; 1.0190x over previous
//
#include <hip/hip_runtime.h>
#include <hip/hip_bf16.h>
#include <hip/hip_fp16.h>

#define NNODES 100000
#define NEDGES 2500000
#define CIN 32
#define CHID 16
#define COUT 64
#define NGRAPH 64

#define NPB 256                 // nodes per bucket
#define NBUCKET 391             // ceil(100000/256)
#define BCAP 7424               // per-bucket raw capacity (mean 6394, ~13 sigma)
#define BSTRIDE 9472            // per-bucket padded csr stride (max 7424+256*7=9216)
#define TILE 8192               // edges per binsort block
#define NTB 306                 // ceil(2.5M/8192)
#define AGG_BLOCKS 1563         // ceil(100000/64), 64 nodes per block (4 lanes/node)

// ---------------- workspace layout (4-byte units) ----------------------------
// gcnt  [0, 512)               int, zeroed (391 used)
// ginv  [1024, 1088)           f32
// offs  [1088, 101088)         int (padded csr start per node)
// deg   [101120, 201120)       int (true in-degree)
// csr   [201216, 3904768)      int, per-bucket stride BSTRIDE, pad = NNODES
// ebuf  [3904768, 6807552)     int packed (src<<8)|dst_local
// xlh   [6807552, 7607560)     f16 (N+1)*16 (row N = zeros)
// xr    [7607560, 9207560)     f32 N*16
// hh    [9207560, 10007568)    f16 (N+1)*16 (row N = zeros)  => 40.0 MB
#define OFF_GCNT  0
#define OFF_GINV  1024
#define OFF_OFFS  1088
#define OFF_DEG   101120
#define OFF_CSR   201216
#define OFF_EBUF  3904768
#define OFF_XLH   6807552
#define OFF_XR    7607560
#define OFF_HH    9207560

__device__ inline float4 unpack_h4(uint2 v) {
    __half2 p0 = *reinterpret_cast<__half2*>(&v.x);
    __half2 p1 = *reinterpret_cast<__half2*>(&v.y);
    float2 f0 = __half22float2(p0), f1 = __half22float2(p1);
    return make_float4(f0.x, f0.y, f1.x, f1.y);
}

__device__ inline uint2 pack_h4(float a, float b, float c, float d) {
    __half2 h0 = __floats2half2_rn(a, b);
    __half2 h1 = __floats2half2_rn(c, d);
    uint2 r;
    r.x = *reinterpret_cast<unsigned int*>(&h0);
    r.y = *reinterpret_cast<unsigned int*>(&h1);
    return r;
}

// LDS counting-sort binning (R5/R6-proven): dense sequential bucket-run writes.
__global__ __launch_bounds__(512) void binsort(const int* __restrict__ src,
                                               const int* __restrict__ dst,
                                               int* __restrict__ gcnt,
                                               int* __restrict__ ebuf) {
    __shared__ int hist[NBUCKET];
    __shared__ int binstart[NBUCKET];
    __shared__ int cursor[NBUCKET];
    __shared__ int gbase[NBUCKET];
    __shared__ int tmp[512];
    __shared__ int sbuf[TILE];
    int tid = threadIdx.x;
    int base = blockIdx.x * TILE;
    int cnt = min(NEDGES - base, TILE);
    for (int i = tid; i < NBUCKET; i += 512) hist[i] = 0;
    __syncthreads();
    int v[16], k[16];
#pragma unroll
    for (int j = 0; j < 16; j++) {
        int i = tid + j * 512;
        if (i < cnt) {
            int d = dst[base + i], s = src[base + i];
            k[j] = d >> 8;
            v[j] = (s << 8) | (d & 255);
            atomicAdd(&hist[k[j]], 1);
        }
    }
    __syncthreads();
    int hv = (tid < NBUCKET) ? hist[tid] : 0;
    tmp[tid] = hv;
    __syncthreads();
#pragma unroll
    for (int dd = 1; dd < 512; dd <<= 1) {
        int u = (tid >= dd) ? tmp[tid - dd] : 0;
        __syncthreads();
        tmp[tid] += u;
        __syncthreads();
    }
    if (tid < NBUCKET) {
        int excl = tmp[tid] - hv;
        binstart[tid] = excl;
        cursor[tid] = excl;
        gbase[tid] = (hv > 0) ? atomicAdd(&gcnt[tid], hv) : 0;
    }
    __syncthreads();
#pragma unroll
    for (int j = 0; j < 16; j++) {
        int i = tid + j * 512;
        if (i < cnt) {
            int p = atomicAdd(&cursor[k[j]], 1);
            sbuf[p] = v[j];
        }
    }
    __syncthreads();
    int wave = tid >> 6, lane = tid & 63;
    for (int b = wave; b < NBUCKET; b += 8) {
        int c2 = hist[b];
        if (c2 == 0) continue;
        int g = gbase[b];
        int gs = min(g, BCAP);
        int ncopy = min(g + c2, BCAP) - gs;    // overflow-guarded
        int ls = binstart[b];
        int* dp = ebuf + (size_t)b * BCAP + gs;
        for (int i = lane; i < ncopy; i += 64) dp[i] = sbuf[ls + i];
    }
}

__device__ inline int lower_bound_i(const int* __restrict__ b, int n, int key) {
    int lo = 0, hi = n;
    while (lo < hi) {
        int m = (lo + hi) >> 1;
        if (b[m] < key) lo = m + 1; else hi = m;
    }
    return lo;
}

__global__ void graph_inv(const int* __restrict__ batch, float* __restrict__ ginv) {
    int g = threadIdx.x;
    if (g >= NGRAPH) return;
    int s = lower_bound_i(batch, NNODES, g);
    int e = lower_bound_i(batch, NNODES, g + 1);
    ginv[g] = 1.0f / (float)max(e - s, 1);
}

// counting-sort each bucket run (LDS-staged once) into a PADDED CSR:
// each node's run is rounded up to a multiple of 8, slack filled with the
// sentinel node NNODES (whose feature rows are zero) -> agg loops have no
// remainder and no divergent tail. Fixed per-bucket stride: no global scan.
__global__ __launch_bounds__(256) void bucket_build(const int* __restrict__ gcnt,
                                                    const int* __restrict__ ebuf,
                                                    int* __restrict__ csr,
                                                    int* __restrict__ offs,
                                                    int* __restrict__ deg) {
    __shared__ int sbuf[BCAP];            // 29.7 KB
    __shared__ int hist[NPB];
    __shared__ int tmp[NPB];
    int b = blockIdx.x, tid = threadIdx.x;
    int nodes0 = b << 8;
    int nloc = min(NPB, NNODES - nodes0);
    int cnt = min(gcnt[b], BCAP);
    hist[tid] = 0;
    const int* run = ebuf + (size_t)b * BCAP;
    for (int i = tid; i < cnt; i += 256) sbuf[i] = run[i];
    __syncthreads();
    for (int i = tid; i < cnt; i += 256) atomicAdd(&hist[sbuf[i] & 255], 1);
    __syncthreads();
    int d  = hist[tid];
    int pc = (d + 7) & ~7;                // padded count
    tmp[tid] = pc;
    __syncthreads();
#pragma unroll
    for (int s = 1; s < NPB; s <<= 1) {
        int u = (tid >= s) ? tmp[tid - s] : 0;
        __syncthreads();
        tmp[tid] += u;
        __syncthreads();
    }
    int excl = tmp[tid] - pc;
    hist[tid] = excl;                     // becomes running cursor
    if (tid < nloc) {
        offs[nodes0 + tid] = b * BSTRIDE + excl;
        deg[nodes0 + tid] = d;
    }
    __syncthreads();
    int* bcsr = csr + (size_t)b * BSTRIDE;
    for (int i = tid; i < cnt; i += 256) {
        int v = sbuf[i];
        int p = atomicAdd(&hist[v & 255], 1);
        bcsr[p] = v >> 8;
    }
    __syncthreads();
    // pad fill: cursor is now excl+d; fill up to excl+pc with sentinel
    int fs = hist[tid], fe = excl + pc;
    for (int k2 = fs; k2 < fe; k2++) bcsr[k2] = NNODES;
}

// xl(f16) = x @ w1_l.T ; xr(f32) = x @ w1_r.T + b1 ; zero the xl pad row
__global__ __launch_bounds__(256) void transform1(const float* __restrict__ x,
                                                  const float* __restrict__ w1l,
                                                  const float* __restrict__ b1,
                                                  const float* __restrict__ w1r,
                                                  __half2* __restrict__ xlh2,
                                                  float* __restrict__ xr) {
    __shared__ float wl[CHID * CIN];
    __shared__ float wr[CHID * CIN];
    __shared__ float bs[CHID];
    for (int i = threadIdx.x; i < CHID * CIN; i += 256) { wl[i] = w1l[i]; wr[i] = w1r[i]; }
    if (threadIdx.x < CHID) bs[threadIdx.x] = b1[threadIdx.x];
    if (blockIdx.x == 0 && threadIdx.x < 8)
        xlh2[(size_t)NNODES * 8 + threadIdx.x] = __floats2half2_rn(0.f, 0.f);
    __syncthreads();
    int n = blockIdx.x * 256 + threadIdx.x;
    if (n >= NNODES) return;
    float xv[CIN];
    const float4* x4 = (const float4*)(x + (size_t)n * CIN);
#pragma unroll
    for (int q = 0; q < CIN / 4; q++) {
        float4 v = x4[q];
        xv[4*q] = v.x; xv[4*q+1] = v.y; xv[4*q+2] = v.z; xv[4*q+3] = v.w;
    }
    float oL[CHID];
#pragma unroll
    for (int o = 0; o < CHID; o++) {
        float aL = 0.f, aR = bs[o];
#pragma unroll
        for (int i = 0; i < CIN; i++) {
            aL = fmaf(wl[o * CIN + i], xv[i], aL);
            aR = fmaf(wr[o * CIN + i], xv[i], aR);
        }
        oL[o] = aL;
        xr[(size_t)n * CHID + o] = aR;
    }
#pragma unroll
    for (int q = 0; q < CHID / 2; q++)
        xlh2[(size_t)n * 8 + q] = __floats2half2_rn(oL[2*q], oL[2*q+1]);
}

// layer-1 aggregate + finalize: h(f16) = relu(mean_in(xl[src]) + xr)
// 4 lanes per node, 8B uint2 gathers (16 edges per wave-instr), padded CSR:
// no remainder loop. Also zeroes the hh pad row for agg2.
__global__ __launch_bounds__(256) void agg1_fused(const int* __restrict__ offs,
                                                  const int* __restrict__ deg,
                                                  const int* __restrict__ csr,
                                                  const uint2* __restrict__ xlh4,
                                                  const float* __restrict__ xr,
                                                  uint2* __restrict__ hh4) {
    if (blockIdx.x == 0 && threadIdx.x < 4) {
        uint2 z; z.x = 0u; z.y = 0u;
        hh4[(size_t)NNODES * 4 + threadIdx.x] = z;
    }
    int node = blockIdx.x * 64 + (threadIdx.x >> 2);
    int c4 = threadIdx.x & 3;
    if (node >= NNODES) return;
    int s0 = offs[node];
    int d  = deg[node];
    int iters = (d + 7) >> 3;
    float4 a0 = {0,0,0,0}, a1 = {0,0,0,0}, a2 = {0,0,0,0}, a3 = {0,0,0,0};
    float4 a4 = {0,0,0,0}, a5 = {0,0,0,0}, a6 = {0,0,0,0}, a7 = {0,0,0,0};
    const int* cp = csr + s0;
    for (int it = 0; it < iters; it++, cp += 8) {
        int sA = cp[0], sB = cp[1], sC = cp[2], sD = cp[3];
        int sE = cp[4], sF = cp[5], sG = cp[6], sH = cp[7];
        float4 fA = unpack_h4(xlh4[(size_t)sA * 4 + c4]);
        float4 fB = unpack_h4(xlh4[(size_t)sB * 4 + c4]);
        float4 fC = unpack_h4(xlh4[(size_t)sC * 4 + c4]);
        float4 fD = unpack_h4(xlh4[(size_t)sD * 4 + c4]);
        float4 fE = unpack_h4(xlh4[(size_t)sE * 4 + c4]);
        float4 fF = unpack_h4(xlh4[(size_t)sF * 4 + c4]);
        float4 fG = unpack_h4(xlh4[(size_t)sG * 4 + c4]);
        float4 fH = unpack_h4(xlh4[(size_t)sH * 4 + c4]);
        a0 += fA; a1 += fB; a2 += fC; a3 += fD;
        a4 += fE; a5 += fF; a6 += fG; a7 += fH;
    }
    float4 s = ((a0 + a1) + (a2 + a3)) + ((a4 + a5) + (a6 + a7));
    float inv = 1.0f / (float)max(d, 1);
    float4 r = *(const float4*)(xr + (size_t)node * CHID + c4 * 4);
    float h0 = fmaxf(fmaf(s.x, inv, r.x), 0.f);
    float h1 = fmaxf(fmaf(s.y, inv, r.y), 0.f);
    float h2 = fmaxf(fmaf(s.z, inv, r.z), 0.f);
    float h3 = fmaxf(fmaf(s.w, inv, r.w), 0.f);
    hh4[(size_t)node * 4 + c4] = pack_h4(h0, h1, h2, h3);
}

// layer-2 aggregate + output transform + fused graph pooling (4 lanes/node)
__global__ __launch_bounds__(256) void agg2_pool(const int* __restrict__ offs,
                                                 const int* __restrict__ deg,
                                                 const int* __restrict__ csr,
                                                 const uint2* __restrict__ hh4,
                                                 const float* __restrict__ w2l,
                                                 const float* __restrict__ b2,
                                                 const float* __restrict__ w2r,
                                                 const int* __restrict__ batch,
                                                 const float* __restrict__ ginv,
                                                 float* __restrict__ out) {
    __shared__ float wlT[CHID * COUT];      // transposed: contiguous in o
    __shared__ float wrT[CHID * COUT];
    __shared__ float bs[COUT];
    __shared__ float mean_s[64 * CHID];
    __shared__ float pool[4 * COUT];        // 64-node window spans <=2 graphs
    __shared__ int used[4];
    for (int idx = threadIdx.x; idx < CHID * COUT; idx += 256) {
        int i = idx >> 6, o = idx & 63;
        wlT[idx] = w2l[o * CHID + i];
        wrT[idx] = w2r[o * CHID + i];
    }
    if (threadIdx.x < COUT) bs[threadIdx.x] = b2[threadIdx.x];
    for (int idx = threadIdx.x; idx < 4 * COUT; idx += 256) pool[idx] = 0.f;
    if (threadIdx.x < 4) used[threadIdx.x] = 0;
    __syncthreads();

    int g = threadIdx.x >> 2;               // 0..63 node slots
    int c4 = threadIdx.x & 3;
    int node = blockIdx.x * 64 + g;
    bool valid = node < NNODES;
    int nd = valid ? node : NNODES - 1;
    int gbase = batch[blockIdx.x * 64];
    int gid = batch[nd];
    int gloc = min(gid - gbase, 3);
    float gw = ginv[gid];
    if (valid && c4 == 0) used[gloc] = 1;

    int s0 = offs[nd];
    int d  = deg[nd];
    int iters = (d + 7) >> 3;
    float4 a0 = {0,0,0,0}, a1 = {0,0,0,0}, a2 = {0,0,0,0}, a3 = {0,0,0,0};
    float4 a4 = {0,0,0,0}, a5 = {0,0,0,0}, a6 = {0,0,0,0}, a7 = {0,0,0,0};
    const int* cp = csr + s0;
    for (int it = 0; it < iters; it++, cp += 8) {
        int sA = cp[0], sB = cp[1], sC = cp[2], sD = cp[3];
        int sE = cp[4], sF = cp[5], sG = cp[6], sH = cp[7];
        float4 fA = unpack_h4(hh4[(size_t)sA * 4 + c4]);
        float4 fB = unpack_h4(hh4[(size_t)sB * 4 + c4]);
        float4 fC = unpack_h4(hh4[(size_t)sC * 4 + c4]);
        float4 fD = unpack_h4(hh4[(size_t)sD * 4 + c4]);
        float4 fE = unpack_h4(hh4[(size_t)sE * 4 + c4]);
        float4 fF = unpack_h4(hh4[(size_t)sF * 4 + c4]);
        float4 fG = unpack_h4(hh4[(size_t)sG * 4 + c4]);
        float4 fH = unpack_h4(hh4[(size_t)sH * 4 + c4]);
        a0 += fA; a1 += fB; a2 += fC; a3 += fD;
        a4 += fE; a5 += fF; a6 += fG; a7 += fH;
    }
    float4 s = ((a0 + a1) + (a2 + a3)) + ((a4 + a5) + (a6 + a7));
    float inv = 1.0f / (float)max(d, 1);
    float4 mn = make_float4(s.x * inv, s.y * inv, s.z * inv, s.w * inv);
    ((float4*)mean_s)[g * 4 + c4] = mn;
    __syncthreads();

    // own h row + group mean from LDS
    float hv[CHID], m[CHID];
#pragma unroll
    for (int q = 0; q < 4; q++) {
        float4 f = unpack_h4(hh4[(size_t)nd * 4 + q]);
        hv[4*q] = f.x; hv[4*q+1] = f.y; hv[4*q+2] = f.z; hv[4*q+3] = f.w;
    }
#pragma unroll
    for (int i = 0; i < CHID; i++) m[i] = mean_s[g * CHID + i];

    if (valid) {
#pragma unroll
        for (int k = 0; k < 16; k++) {
            int o = c4 + 4 * k;
            float acc = bs[o];
#pragma unroll
            for (int i = 0; i < CHID; i++) {
                acc = fmaf(wlT[i * COUT + o], m[i], acc);
                acc = fmaf(wrT[i * COUT + o], hv[i], acc);
            }
            atomicAdd(&pool[gloc * COUT + o], acc * gw);
        }
    }
    __syncthreads();
    for (int idx = threadIdx.x; idx < 4 * COUT; idx += 256) {
        int row = idx >> 6;
        if (used[row]) atomicAdd(&out[(gbase + row) * COUT + (idx & 63)], pool[idx]);
    }
}

extern "C" void kernel_launch(void* const* d_in, const int* in_sizes, int n_in,
                              void* d_out, int out_size, void* d_ws, size_t ws_size,
                              hipStream_t stream) {
    const float* x    = (const float*)d_in[0];
    const int*   ei   = (const int*)d_in[1];   // [2, E] int32
    const int*   batch= (const int*)d_in[2];
    const float* w1l  = (const float*)d_in[3];
    const float* b1   = (const float*)d_in[4];
    const float* w1r  = (const float*)d_in[5];
    const float* w2l  = (const float*)d_in[6];
    const float* b2   = (const float*)d_in[7];
    const float* w2r  = (const float*)d_in[8];
    float* out = (float*)d_out;

    const int* src = ei;
    const int* dst = ei + NEDGES;

    int*     ws_i = (int*)d_ws;
    float*   ws_f = (float*)d_ws;
    int*     gcnt = ws_i + OFF_GCNT;
    float*   ginv = ws_f + OFF_GINV;
    int*     offs = ws_i + OFF_OFFS;
    int*     deg  = ws_i + OFF_DEG;
    int*     csr  = ws_i + OFF_CSR;
    int*     ebuf = ws_i + OFF_EBUF;
    __half2* xlh2 = (__half2*)(ws_i + OFF_XLH);
    uint2*   xlh4 = (uint2*)(ws_i + OFF_XLH);
    float*   xr   = ws_f + OFF_XR;
    uint2*   hh4  = (uint2*)(ws_i + OFF_HH);

    (void)hipMemsetAsync(gcnt, 0, 512 * sizeof(int), stream);
    (void)hipMemsetAsync(out, 0, NGRAPH * COUT * sizeof(float), stream);

    int nbl = (NNODES + 255) / 256;   // 391

    binsort     <<<NTB, 512, 0, stream>>>(src, dst, gcnt, ebuf);
    transform1  <<<nbl, 256, 0, stream>>>(x, w1l, b1, w1r, xlh2, xr);
    graph_inv   <<<1, 64, 0, stream>>>(batch, ginv);
    bucket_build<<<NBUCKET, 256, 0, stream>>>(gcnt, ebuf, csr, offs, deg);
    agg1_fused  <<<AGG_BLOCKS, 256, 0, stream>>>(offs, deg, csr, xlh4, xr, hh4);
    agg2_pool   <<<AGG_BLOCKS, 256, 0, stream>>>(offs, deg, csr, hh4, w2l, b2, w2r,
                                                 batch, ginv, out);
}